// Round 22
// baseline (76.655 us; speedup 1.0000x reference)
//
#include <hip/hip_runtime.h>
#include <hip/hip_bf16.h>
#include <math.h>

#define B_ 4
#define T_ 2048
#define C_ 1024
#define H_ 128
#define SCALE 0.088388347648318447f   // 1/sqrt(128)

typedef unsigned short u16;
typedef __bf16 bf16x8 __attribute__((ext_vector_type(8)));
typedef float  f32x4  __attribute__((ext_vector_type(4)));
typedef u16    u16x8  __attribute__((ext_vector_type(8)));
typedef u16    u16x4  __attribute__((ext_vector_type(4)));

// ws byte offsets (ws ~256MB; all regions disjoint)
#define PO_OFF  0u            // bf16 [4][144][64][128] =  9,437,184 B
#define ML_OFF  18874368u     // f32 [4][144][2][64]    =    294,912 B
#define WBT_OFF 19169280u     // bf16 [3][128][1024]    =    786,432 B
#define QB_OFF  19955712u     // bf16 [4][2048][128]    =  2,097,152 B
#define KB_OFF  22052864u     // bf16 [4][2048][128]    =  2,097,152 B
#define VT_OFF  24150016u     // bf16 [4][128][2048]    =  2,097,152 B

__device__ __forceinline__ u16 f2bf(float f) {
    __hip_bfloat16 h = __float2bfloat16(f);
    return __builtin_bit_cast(u16, h);
}
__device__ __forceinline__ float bf2f(u16 u) {
    unsigned v = (unsigned)u << 16;          // bf16 -> f32 is exact
    return __builtin_bit_cast(float, v);
}

// async global->LDS, 16B per lane. lds dst must be wave-uniform base (HW adds lane*16).
__device__ __forceinline__ void load_lds16(const void* g, void* l) {
    __builtin_amdgcn_global_load_lds(
        (const __attribute__((address_space(1))) unsigned int*)g,
        (__attribute__((address_space(3))) unsigned int*)l, 16, 0, 0);
}

// ---------------------------------------------------------------------------
// convert + transpose W: wbT[s][n][k] = W_s[k][n] (bf16), SCALE folded into Wq
// ---------------------------------------------------------------------------
__global__ __launch_bounds__(256) void convert_w(const float* __restrict__ Wq,
                                                 const float* __restrict__ Wk,
                                                 const float* __restrict__ Wv,
                                                 u16* __restrict__ wbT) {
    const int id = blockIdx.x * 256 + threadIdx.x;      // < 3*131072
    const int s = id >> 17;
    const int r = id & 131071;
    const int k = r >> 7, n = r & 127;
    const float* W = (s == 0) ? Wq : (s == 1) ? Wk : Wv;
    float v = W[k * 128 + n];
    if (s == 0) v *= SCALE;
    wbT[(s << 17) + (n << 10) + k] = f2bf(v);
}

// ---------------------------------------------------------------------------
// QKV GEMM, BK=128 (8 K-steps, 16 MFMA/wave/step — barrier count halved vs
// r13). bf16 MFMA, fp32 x converted in-kernel, 2-deep pipelined staging.
// grid (256, 3), block 256 (4 waves, 2Mx2N). Tile 32(M)x128(N).
// LDS: xs 2x8KB + ws 2x32KB = 80KB -> 2 blocks/CU.
// ---------------------------------------------------------------------------
__global__ __launch_bounds__(256) void gemm_qkv(
    const float* __restrict__ x, const u16* __restrict__ wbT,
    u16* __restrict__ qb, u16* __restrict__ kb, u16* __restrict__ vT)
{
    __shared__ u16 xs[2][4096];    // [32][128] bf16, 256B rows, swizzle ^((row&7)<<4)
    __shared__ u16 ws[2][16384];   // [128 n][128 k] bf16, 256B rows, same swizzle

    const int tid = threadIdx.x;
    const int w = tid >> 6, lane = tid & 63, lg = lane >> 4, lr = lane & 15;
    const int wm = w >> 1, wn = w & 1;
    const int s = blockIdx.y;
    const int m0 = blockIdx.x * 32;
    const u16* wsrc = wbT + (s << 17);

    // x staging role: 8 threads per row, 16 fp32 (4 float4) per thread
    const int xrow = tid >> 3;       // 0..31
    const int xseg = tid & 7;        // 0..7
    const float* xbase = x + (size_t)(m0 + xrow) * C_ + xseg * 16;
    const unsigned xsw = ((unsigned)xrow & 7u) << 4;

    // W staging addresses (pre-swizzled source), 8 x 1KB chunks per wave
    unsigned wro[8], wco[8];
#pragma unroll
    for (int i = 0; i < 8; ++i) {
        const unsigned o = (unsigned)(w * 8 + i) * 1024u + (unsigned)lane * 16u;
        const unsigned o2 = o ^ (((o >> 8) & 7u) << 4);
        wro[i] = o2 >> 8; wco[i] = (o2 & 255u) >> 1;
    }

    f32x4 acc[4] = {};

    // ---- prologue: stage k0=0 into buf 0
    {
        const float4 f0 = ((const float4*)xbase)[0], f1 = ((const float4*)xbase)[1];
        const float4 f2 = ((const float4*)xbase)[2], f3 = ((const float4*)xbase)[3];
#pragma unroll
        for (int i = 0; i < 8; ++i)
            load_lds16(wsrc + (size_t)wro[i] * C_ + wco[i], &ws[0][(w * 8 + i) * 512]);
        u16x8 lo, hi;
        lo[0] = f2bf(f0.x); lo[1] = f2bf(f0.y); lo[2] = f2bf(f0.z); lo[3] = f2bf(f0.w);
        lo[4] = f2bf(f1.x); lo[5] = f2bf(f1.y); lo[6] = f2bf(f1.z); lo[7] = f2bf(f1.w);
        hi[0] = f2bf(f2.x); hi[1] = f2bf(f2.y); hi[2] = f2bf(f2.z); hi[3] = f2bf(f2.w);
        hi[4] = f2bf(f3.x); hi[5] = f2bf(f3.y); hi[6] = f2bf(f3.z); hi[7] = f2bf(f3.w);
        char* rb = (char*)xs[0] + xrow * 256;
        *(u16x8*)(rb + (((unsigned)xseg * 32 + 0) ^ xsw)) = lo;
        *(u16x8*)(rb + (((unsigned)xseg * 32 + 16) ^ xsw)) = hi;
    }
    __syncthreads();

    int buf = 0;
    for (int k0 = 0; k0 < C_; k0 += 128) {
        const bool pf = (k0 + 128 < C_);
        float4 g0, g1, g2, g3;
        if (pf) {
            const float* xn = xbase + k0 + 128;
            g0 = ((const float4*)xn)[0]; g1 = ((const float4*)xn)[1];
            g2 = ((const float4*)xn)[2]; g3 = ((const float4*)xn)[3];
#pragma unroll
            for (int i = 0; i < 8; ++i)
                load_lds16(wsrc + (size_t)wro[i] * C_ + (k0 + 128) + wco[i],
                           &ws[buf ^ 1][(w * 8 + i) * 512]);
        }

        // ---- compute from buf: 4 kc x 4 ni = 16 MFMA per wave
        const int arow = wm * 16 + lr;
        const unsigned asw = ((unsigned)arow & 7u) << 4;
#pragma unroll
        for (int kc = 0; kc < 4; ++kc) {
            const unsigned kb_ = (unsigned)(kc * 64 + lg * 16);
            const bf16x8 af = *(const bf16x8*)((const char*)xs[buf] + arow * 256 + (kb_ ^ asw));
            bf16x8 bfr[4];
#pragma unroll
            for (int ni = 0; ni < 4; ++ni) {
                const int n = wn * 64 + ni * 16 + lr;
                bfr[ni] = *(const bf16x8*)((const char*)ws[buf] + n * 256 + (kb_ ^ (((unsigned)n & 7u) << 4)));
            }
#pragma unroll
            for (int ni = 0; ni < 4; ++ni)
                acc[ni] = __builtin_amdgcn_mfma_f32_16x16x32_bf16(af, bfr[ni], acc[ni], 0, 0, 0);
        }

        // ---- land converted x(k0+128) into buf^1
        if (pf) {
            u16x8 lo, hi;
            lo[0] = f2bf(g0.x); lo[1] = f2bf(g0.y); lo[2] = f2bf(g0.z); lo[3] = f2bf(g0.w);
            lo[4] = f2bf(g1.x); lo[5] = f2bf(g1.y); lo[6] = f2bf(g1.z); lo[7] = f2bf(g1.w);
            hi[0] = f2bf(g2.x); hi[1] = f2bf(g2.y); hi[2] = f2bf(g2.z); hi[3] = f2bf(g2.w);
            hi[4] = f2bf(g3.x); hi[5] = f2bf(g3.y); hi[6] = f2bf(g3.z); hi[7] = f2bf(g3.w);
            char* rb = (char*)xs[buf ^ 1] + xrow * 256;
            *(u16x8*)(rb + (((unsigned)xseg * 32 + 0) ^ xsw)) = lo;
            *(u16x8*)(rb + (((unsigned)xseg * 32 + 16) ^ xsw)) = hi;
        }
        __syncthreads();
        buf ^= 1;
    }

    if (s < 2) {
        u16* dst = (s == 0) ? qb : kb;
#pragma unroll
        for (int ni = 0; ni < 4; ++ni) {
            const int trow = m0 + wm * 16 + lg * 4;
            const int col = wn * 64 + ni * 16 + lr;
#pragma unroll
            for (int r = 0; r < 4; ++r)
                dst[(size_t)(trow + r) * H_ + col] = f2bf(acc[ni][r]);
        }
    } else {
        // v stored transposed: vT[b][d][t]
#pragma unroll
        for (int ni = 0; ni < 4; ++ni) {
            const int trow = m0 + wm * 16 + lg * 4;
            const int bb = trow >> 11, t = trow & 2047;
            const int d = wn * 64 + ni * 16 + lr;
            u16x4 pk;
            pk[0] = f2bf(acc[ni][0]); pk[1] = f2bf(acc[ni][1]);
            pk[2] = f2bf(acc[ni][2]); pk[3] = f2bf(acc[ni][3]);
            *(u16x4*)&vT[((size_t)bb * 128 + d) * 2048 + t] = pk;
        }
    }
}

// ---------------------------------------------------------------------------
// Flash attention, KVBLK=64 (r21 version, best measured): split-K chunks of
// 4 big-tiles (256 kv). 64 q-rows/block (4 waves), double-buffered K/V,
// defer-max softmax, bf16 partials. grid (32, 8, 4), block 256.
// ---------------------------------------------------------------------------
__global__ __launch_bounds__(256) void attn_split(
    const u16* __restrict__ qb, const u16* __restrict__ kb,
    const u16* __restrict__ vT, u16* __restrict__ po, float* __restrict__ ml)
{
    __shared__ u16 ks[2][8192];      // [64 kv][128 d] bf16, 256B rows, swizzle ^((row&7)<<4)
    __shared__ u16 vs[2][9216];      // 2 halves x [128 d][seg-interleaved 32kv], 72B rows

    const int jt = blockIdx.x, sp = blockIdx.y, b = blockIdx.z;
    const int nt_all = jt + 1;                  // 64-kv tiles covering the causal range
    const int kt0 = sp * 4;
    if (kt0 >= nt_all) return;
    const int kt_end = min(kt0 + 4, nt_all);

    const int tid = threadIdx.x;
    const int w = tid >> 6, lane = tid & 63, lg = lane >> 4, lr = lane & 15;
    const int qrow_base = jt * 64 + w * 16;

    const u16* kbB = kb + ((size_t)(b << 11)) * H_;
    const u16* vbB = vT + (size_t)b * 128 * 2048;

    // K staging: 4 x 1KB chunks per wave (16KB tile), pre-swizzled source
    unsigned krow[4], kcolb[4];
#pragma unroll
    for (int i = 0; i < 4; ++i) {
        const unsigned o_ = (unsigned)(w * 4 + i) * 1024u + (unsigned)lane * 16u;
        const unsigned o2 = o_ ^ (((o_ >> 8) & 7u) << 4);
        krow[i] = o2 >> 8; kcolb[i] = o2 & 255u;
    }
    // V staging: per half, 2 x u16x8 per thread
    int vd[2], vc[2];
#pragma unroll
    for (int i = 0; i < 2; ++i) {
        const int idx = i * 256 + tid;
        vd[i] = idx >> 2; vc[i] = idx & 3;
    }

    // Q fragments: d-slot map = kc*32 + lg*8 + j  (matches K-frag map)
    const u16* qp = qb + ((size_t)(b << 11) + qrow_base + lr) * H_;
    bf16x8 qf[4];
#pragma unroll
    for (int kc = 0; kc < 4; ++kc)
        qf[kc] = *(const bf16x8*)&qp[kc * 32 + lg * 8];

    u16x8 vr[4];   // [half][i]
    // ---- prologue: stage tile kt0 into buffer 0
    {
        const u16* kbase = kbB + (size_t)kt0 * 64 * H_;
#pragma unroll
        for (int i = 0; i < 4; ++i)
            load_lds16((const char*)kbase + krow[i] * 256 + kcolb[i], &ks[0][(w * 4 + i) * 512]);
        const u16* vbase = vbB + (size_t)kt0 * 64;
#pragma unroll
        for (int h = 0; h < 2; ++h)
#pragma unroll
            for (int i = 0; i < 2; ++i)
                vr[h * 2 + i] = *(const u16x8*)&vbase[(size_t)vd[i] * 2048 + h * 32 + vc[i] * 8];
#pragma unroll
        for (int h = 0; h < 2; ++h)
#pragma unroll
            for (int i = 0; i < 2; ++i) {
                char* rb = (char*)vs[0] + h * 9216 + vd[i] * 72 + (vc[i] & 2) * 4;
                *(u16x4*)(rb + ((2 * vc[i]) & 3) * 16)     = __builtin_shufflevector(vr[h * 2 + i], vr[h * 2 + i], 0, 1, 2, 3);
                *(u16x4*)(rb + ((2 * vc[i] + 1) & 3) * 16) = __builtin_shufflevector(vr[h * 2 + i], vr[h * 2 + i], 4, 5, 6, 7);
            }
    }
    __syncthreads();

    f32x4 o[8] = {};
    float m_run = -1e30f, l_run = 0.f;
    int cur = 0;

    for (int kt = kt0; kt < kt_end; ++kt) {
        const bool pf = (kt + 1 < kt_end);
        // ---- issue prefetch of tile kt+1
        if (pf) {
            const u16* kbase = kbB + (size_t)(kt + 1) * 64 * H_;
#pragma unroll
            for (int i = 0; i < 4; ++i)
                load_lds16((const char*)kbase + krow[i] * 256 + kcolb[i],
                           &ks[cur ^ 1][(w * 4 + i) * 512]);
            const u16* vbase = vbB + (size_t)(kt + 1) * 64;
#pragma unroll
            for (int h = 0; h < 2; ++h)
#pragma unroll
                for (int i = 0; i < 2; ++i)
                    vr[h * 2 + i] = *(const u16x8*)&vbase[(size_t)vd[i] * 2048 + h * 32 + vc[i] * 8];
        }

        // ---- S^T = K @ Q^T : four 16-kv subtiles
        f32x4 sS[4] = {};
        const unsigned swz = ((unsigned)lr & 7u) << 4;
#pragma unroll
        for (int kc = 0; kc < 4; ++kc) {
            const unsigned byte = ((unsigned)(kc * 64 + lg * 16)) ^ swz;
#pragma unroll
            for (int si = 0; si < 4; ++si) {
                const bf16x8 kf = *(const bf16x8*)((const char*)ks[cur] + si * 4096 + lr * 256 + byte);
                sS[si] = __builtin_amdgcn_mfma_f32_16x16x32_bf16(kf, qf[kc], sS[si], 0, 0, 0);
            }
        }

        // causal mask (boundary tiles only), global indices
        if (kt * 64 + 63 > qrow_base) {
            const int qg = qrow_base + lr;
#pragma unroll
            for (int si = 0; si < 4; ++si) {
                const int kvb = kt * 64 + si * 16 + lg * 4;
#pragma unroll
                for (int r = 0; r < 4; ++r)
                    if (kvb + r > qg) sS[si][r] = -INFINITY;
            }
        }

        // online softmax with defer-max (q-row = lr, replicated across 4 lane-groups)
        float mt = fmaxf(fmaxf(fmaxf(sS[0][0], sS[0][1]), fmaxf(sS[0][2], sS[0][3])),
                         fmaxf(fmaxf(sS[1][0], sS[1][1]), fmaxf(sS[1][2], sS[1][3])));
        mt = fmaxf(mt, fmaxf(fmaxf(fmaxf(sS[2][0], sS[2][1]), fmaxf(sS[2][2], sS[2][3])),
                             fmaxf(fmaxf(sS[3][0], sS[3][1]), fmaxf(sS[3][2], sS[3][3]))));
        mt = fmaxf(mt, __shfl_xor(mt, 16));
        mt = fmaxf(mt, __shfl_xor(mt, 32));
        if (__any(mt > m_run + 8.f)) {
            const float mn = fmaxf(m_run, mt);
            const float f = __expf(m_run - mn);
            const float fb0 = __shfl(f, lg * 4 + 0);
            const float fb1 = __shfl(f, lg * 4 + 1);
            const float fb2 = __shfl(f, lg * 4 + 2);
            const float fb3 = __shfl(f, lg * 4 + 3);
#pragma unroll
            for (int ni = 0; ni < 8; ++ni) {
                o[ni][0] *= fb0; o[ni][1] *= fb1; o[ni][2] *= fb2; o[ni][3] *= fb3;
            }
            l_run *= f;
            m_run = mn;
        }
        float p[16];
#pragma unroll
        for (int si = 0; si < 4; ++si)
#pragma unroll
            for (int r = 0; r < 4; ++r)
                p[si * 4 + r] = __expf(sS[si][r] - m_run);
        float sum = ((p[0] + p[1]) + (p[2] + p[3])) + ((p[4] + p[5]) + (p[6] + p[7]))
                  + ((p[8] + p[9]) + (p[10] + p[11])) + ((p[12] + p[13]) + (p[14] + p[15]));
        sum += __shfl_xor(sum, 16);
        sum += __shfl_xor(sum, 32);
        l_run += sum;

        // P -> bf16 A-frags (slot (g,j) -> kv = 4g + (j&3) + 16*(j>>2) within half)
        bf16x8 pa0, pa1;
#pragma unroll
        for (int r = 0; r < 4; ++r) {
            pa0[r] = (__bf16)p[r];      pa0[4 + r] = (__bf16)p[4 + r];
            pa1[r] = (__bf16)p[8 + r];  pa1[4 + r] = (__bf16)p[12 + r];
        }

        // PV: O[16q x 128d] += P @ V, two chained MFMAs per col-tile
#pragma unroll
        for (int ni = 0; ni < 8; ++ni) {
            const bf16x8 vf0 = *(const bf16x8*)((const char*)vs[cur] + (ni * 16 + lr) * 72 + lg * 16);
            const bf16x8 vf1 = *(const bf16x8*)((const char*)vs[cur] + 9216 + (ni * 16 + lr) * 72 + lg * 16);
            o[ni] = __builtin_amdgcn_mfma_f32_16x16x32_bf16(pa0, vf0, o[ni], 0, 0, 0);
            o[ni] = __builtin_amdgcn_mfma_f32_16x16x32_bf16(pa1, vf1, o[ni], 0, 0, 0);
        }

        // ---- land prefetched V, then barrier (drains K gloads too)
        if (pf) {
#pragma unroll
            for (int h = 0; h < 2; ++h)
#pragma unroll
                for (int i = 0; i < 2; ++i) {
                    char* rb = (char*)vs[cur ^ 1] + h * 9216 + vd[i] * 72 + (vc[i] & 2) * 4;
                    *(u16x4*)(rb + ((2 * vc[i]) & 3) * 16)     = __builtin_shufflevector(vr[h * 2 + i], vr[h * 2 + i], 0, 1, 2, 3);
                    *(u16x4*)(rb + ((2 * vc[i] + 1) & 3) * 16) = __builtin_shufflevector(vr[h * 2 + i], vr[h * 2 + i], 4, 5, 6, 7);
                }
        }
        __syncthreads();
        cur ^= 1;
    }

    // write partials (bf16) — slot math identical to r13
    const int a = jt >> 2, b3 = jt & 3;
    const int slot = (a + 1) * (2 * a + b3) + sp;
    u16* pob = po + (size_t)(b * 144 + slot) * 64 * 128;
#pragma unroll
    for (int ni = 0; ni < 8; ++ni) {
        const int col = ni * 16 + lr;
#pragma unroll
        for (int rj = 0; rj < 4; ++rj)
            pob[(w * 16 + lg * 4 + rj) * 128 + col] = f2bf(o[ni][rj]);
    }
    if (lg == 0) {
        float* mlb = ml + (size_t)(b * 144 + slot) * 128;
        mlb[w * 16 + lr] = m_run;
        mlb[64 + w * 16 + lr] = l_run;
    }
}

// ---------------------------------------------------------------------------
// Combine split-K partials (up to 8, bf16 po). grid (256, 4), block 256.
// ---------------------------------------------------------------------------
__global__ __launch_bounds__(256) void attn_combine(
    const u16* __restrict__ po, const float* __restrict__ ml,
    float* __restrict__ out)
{
    const int rid = (blockIdx.x << 3) + (threadIdx.x >> 5);   // row in batch, 0..2047
    const int b = blockIdx.y;
    const int d4 = (threadIdx.x & 31) * 4;
    const int jt = rid >> 6, row = rid & 63;
    const int a = jt >> 2, b3 = jt & 3;
    const int slot0 = (a + 1) * (2 * a + b3);
    const int c = a + 1;                                       // active splits (1..8)

    float M = -INFINITY;
#pragma unroll
    for (int si = 0; si < 8; ++si)
        if (si < c) M = fmaxf(M, ml[(size_t)(b * 144 + slot0 + si) * 128 + row]);

    float L = 0.f;
    float a0 = 0.f, a1 = 0.f, a2 = 0.f, a3 = 0.f;
#pragma unroll
    for (int si = 0; si < 8; ++si) {
        if (si < c) {
            const float* mlb = ml + (size_t)(b * 144 + slot0 + si) * 128;
            const float wgt = __expf(mlb[row] - M);
            L += wgt * mlb[64 + row];
            const u16x4 t = *(const u16x4*)&po[((size_t)(b * 144 + slot0 + si) * 64 + row) * 128 + d4];
            a0 = fmaf(wgt, bf2f(t[0]), a0); a1 = fmaf(wgt, bf2f(t[1]), a1);
            a2 = fmaf(wgt, bf2f(t[2]), a2); a3 = fmaf(wgt, bf2f(t[3]), a3);
        }
    }
    const float inv = 1.f / L;
    *(float4*)&out[((size_t)(b << 11) + rid) * H_ + d4] =
        make_float4(a0 * inv, a1 * inv, a2 * inv, a3 * inv);
}

extern "C" void kernel_launch(void* const* d_in, const int* in_sizes, int n_in,
                              void* d_out, int out_size, void* d_ws, size_t ws_size,
                              hipStream_t stream) {
    const float* x  = (const float*)d_in[0];
    const float* Wk = (const float*)d_in[1];
    const float* Wq = (const float*)d_in[2];
    const float* Wv = (const float*)d_in[3];
    float* out = (float*)d_out;

    u16* po   = (u16*)((char*)d_ws + PO_OFF);
    float* ml = (float*)((char*)d_ws + ML_OFF);
    u16* wbT  = (u16*)((char*)d_ws + WBT_OFF);
    u16* qb   = (u16*)((char*)d_ws + QB_OFF);
    u16* kb   = (u16*)((char*)d_ws + KB_OFF);
    u16* vT   = (u16*)((char*)d_ws + VT_OFF);

    convert_w<<<1536, 256, 0, stream>>>(Wq, Wk, Wv, wbT);
    gemm_qkv<<<dim3(256, 3), 256, 0, stream>>>(x, wbT, qb, kb, vT);
    attn_split<<<dim3(32, 8, 4), 256, 0, stream>>>(qb, kb, vT, po, ml);
    attn_combine<<<dim3(256, 4), 256, 0, stream>>>(po, ml, out);
}

// Round 23
// 58.998 us; speedup vs baseline: 1.2993x; 1.2993x over previous
//
#include <hip/hip_runtime.h>
#include <hip/hip_bf16.h>
#include <math.h>

#define B_ 4
#define T_ 2048
#define C_ 1024
#define H_ 128
#define SCALE 0.088388347648318447f   // 1/sqrt(128)

typedef unsigned short u16;
typedef __bf16 bf16x8 __attribute__((ext_vector_type(8)));
typedef float  f32x4  __attribute__((ext_vector_type(4)));
typedef u16    u16x8  __attribute__((ext_vector_type(8)));
typedef u16    u16x4  __attribute__((ext_vector_type(4)));

// ws byte offsets (ws ~256MB; all regions disjoint)
#define PO_OFF  0u            // bf16 [4][144][64][128] =  9,437,184 B
#define ML_OFF  18874368u     // f32 [4][144][2][64]    =    294,912 B
#define WBT_OFF 19169280u     // bf16 [3][128][1024]    =    786,432 B
#define QB_OFF  19955712u     // bf16 [4][2048][128]    =  2,097,152 B
#define KB_OFF  22052864u     // bf16 [4][2048][128]    =  2,097,152 B
#define VT_OFF  24150016u     // bf16 [4][128][2048]    =  2,097,152 B

__device__ __forceinline__ u16 f2bf(float f) {
    __hip_bfloat16 h = __float2bfloat16(f);
    return __builtin_bit_cast(u16, h);
}
__device__ __forceinline__ float bf2f(u16 u) {
    unsigned v = (unsigned)u << 16;          // bf16 -> f32 is exact
    return __builtin_bit_cast(float, v);
}

// async global->LDS, 16B per lane. lds dst must be wave-uniform base (HW adds lane*16).
__device__ __forceinline__ void load_lds16(const void* g, void* l) {
    __builtin_amdgcn_global_load_lds(
        (const __attribute__((address_space(1))) unsigned int*)g,
        (__attribute__((address_space(3))) unsigned int*)l, 16, 0, 0);
}

// ---------------------------------------------------------------------------
// convert + transpose W: wbT[s][n][k] = W_s[k][n] (bf16), SCALE folded into Wq
// ---------------------------------------------------------------------------
__global__ __launch_bounds__(256) void convert_w(const float* __restrict__ Wq,
                                                 const float* __restrict__ Wk,
                                                 const float* __restrict__ Wv,
                                                 u16* __restrict__ wbT) {
    const int id = blockIdx.x * 256 + threadIdx.x;      // < 3*131072
    const int s = id >> 17;
    const int r = id & 131071;
    const int k = r >> 7, n = r & 127;
    const float* W = (s == 0) ? Wq : (s == 1) ? Wk : Wv;
    float v = W[k * 128 + n];
    if (s == 0) v *= SCALE;
    wbT[(s << 17) + (n << 10) + k] = f2bf(v);
}

// ---------------------------------------------------------------------------
// QKV GEMM (r13 version, best measured): bf16 MFMA, fp32 x converted
// in-kernel, 2-deep pipelined staging. grid (256, 3), block 256 (4 waves).
// Tile 32(M)x128(N), BK=64.
// ---------------------------------------------------------------------------
__global__ __launch_bounds__(256) void gemm_qkv(
    const float* __restrict__ x, const u16* __restrict__ wbT,
    u16* __restrict__ qb, u16* __restrict__ kb, u16* __restrict__ vT)
{
    __shared__ u16 xs[2][2048];   // [32][64] bf16, 128B rows, swizzle ^((row&7)<<4)
    __shared__ u16 ws[2][8192];   // [128 n][64 k] bf16, 128B rows, same swizzle

    const int tid = threadIdx.x;
    const int w = tid >> 6, lane = tid & 63, lg = lane >> 4, lr = lane & 15;
    const int wm = w >> 1, wn = w & 1;
    const int s = blockIdx.y;
    const int m0 = blockIdx.x * 32;
    const u16* wsrc = wbT + (s << 17);

    // x staging role: 8 threads per row, 8 fp32 (2 float4) per thread
    const int xrow = tid >> 3;       // 0..31
    const int xseg = tid & 7;        // 0..7
    const float* xbase = x + (size_t)(m0 + xrow) * C_ + xseg * 8;
    const unsigned xsw = ((unsigned)xrow & 7u) << 4;

    // W staging addresses (pre-swizzled source), 4 x 1KB chunks per wave
    unsigned wro[4], wco[4];
#pragma unroll
    for (int i = 0; i < 4; ++i) {
        const unsigned o = (unsigned)(w * 4 + i) * 1024u + (unsigned)lane * 16u;
        const unsigned o2 = o ^ (((o >> 7) & 7u) << 4);
        wro[i] = o2 >> 7; wco[i] = (o2 & 127u) >> 1;
    }

    f32x4 acc[4] = {};

    // ---- prologue: stage k0=0 into buf 0
    {
        const float4 f0 = ((const float4*)xbase)[0], f1 = ((const float4*)xbase)[1];
#pragma unroll
        for (int i = 0; i < 4; ++i)
            load_lds16(wsrc + (size_t)wro[i] * C_ + wco[i], &ws[0][(w * 4 + i) * 512]);
        u16x8 pk;
        pk[0] = f2bf(f0.x); pk[1] = f2bf(f0.y); pk[2] = f2bf(f0.z); pk[3] = f2bf(f0.w);
        pk[4] = f2bf(f1.x); pk[5] = f2bf(f1.y); pk[6] = f2bf(f1.z); pk[7] = f2bf(f1.w);
        *(u16x8*)((char*)xs[0] + xrow * 128 + (((unsigned)xseg * 16) ^ xsw)) = pk;
    }
    __syncthreads();

    int buf = 0;
    for (int k0 = 0; k0 < C_; k0 += 64) {
        const bool pf = (k0 + 64 < C_);
        float4 g0, g1;
        if (pf) {
            const float* xn = xbase + k0 + 64;
            g0 = ((const float4*)xn)[0]; g1 = ((const float4*)xn)[1];
#pragma unroll
            for (int i = 0; i < 4; ++i)
                load_lds16(wsrc + (size_t)wro[i] * C_ + (k0 + 64) + wco[i],
                           &ws[buf ^ 1][(w * 4 + i) * 512]);
        }

        // ---- compute from buf
        const int arow = wm * 16 + lr;
        const unsigned asw = ((unsigned)arow & 7u) << 4;
#pragma unroll
        for (int kc = 0; kc < 2; ++kc) {
            const unsigned kb_ = (unsigned)(kc * 64 + lg * 16);
            const bf16x8 af = *(const bf16x8*)((const char*)xs[buf] + arow * 128 + (kb_ ^ asw));
            bf16x8 bfr[4];
#pragma unroll
            for (int ni = 0; ni < 4; ++ni) {
                const int n = wn * 64 + ni * 16 + lr;
                bfr[ni] = *(const bf16x8*)((const char*)ws[buf] + n * 128 + (kb_ ^ (((unsigned)n & 7u) << 4)));
            }
#pragma unroll
            for (int ni = 0; ni < 4; ++ni)
                acc[ni] = __builtin_amdgcn_mfma_f32_16x16x32_bf16(af, bfr[ni], acc[ni], 0, 0, 0);
        }

        // ---- land converted x(k0+64) into buf^1
        if (pf) {
            u16x8 pk;
            pk[0] = f2bf(g0.x); pk[1] = f2bf(g0.y); pk[2] = f2bf(g0.z); pk[3] = f2bf(g0.w);
            pk[4] = f2bf(g1.x); pk[5] = f2bf(g1.y); pk[6] = f2bf(g1.z); pk[7] = f2bf(g1.w);
            *(u16x8*)((char*)xs[buf ^ 1] + xrow * 128 + (((unsigned)xseg * 16) ^ xsw)) = pk;
        }
        __syncthreads();
        buf ^= 1;
    }

    if (s < 2) {
        u16* dst = (s == 0) ? qb : kb;
#pragma unroll
        for (int ni = 0; ni < 4; ++ni) {
            const int trow = m0 + wm * 16 + lg * 4;
            const int col = wn * 64 + ni * 16 + lr;
#pragma unroll
            for (int r = 0; r < 4; ++r)
                dst[(size_t)(trow + r) * H_ + col] = f2bf(acc[ni][r]);
        }
    } else {
        // v stored transposed: vT[b][d][t]
#pragma unroll
        for (int ni = 0; ni < 4; ++ni) {
            const int trow = m0 + wm * 16 + lg * 4;
            const int bb = trow >> 11, t = trow & 2047;
            const int d = wn * 64 + ni * 16 + lr;
            u16x4 pk;
            pk[0] = f2bf(acc[ni][0]); pk[1] = f2bf(acc[ni][1]);
            pk[2] = f2bf(acc[ni][2]); pk[3] = f2bf(acc[ni][3]);
            *(u16x4*)&vT[((size_t)bb * 128 + d) * 2048 + t] = pk;
        }
    }
}

// ---------------------------------------------------------------------------
// Flash attention, KVBLK=64 (r21 version, best measured): split-K chunks of
// 4 big-tiles (256 kv). 64 q-rows/block (4 waves), double-buffered K/V,
// defer-max softmax, bf16 partials. grid (32, 8, 4), block 256.
// ---------------------------------------------------------------------------
__global__ __launch_bounds__(256) void attn_split(
    const u16* __restrict__ qb, const u16* __restrict__ kb,
    const u16* __restrict__ vT, u16* __restrict__ po, float* __restrict__ ml)
{
    __shared__ u16 ks[2][8192];      // [64 kv][128 d] bf16, 256B rows, swizzle ^((row&7)<<4)
    __shared__ u16 vs[2][9216];      // 2 halves x [128 d][seg-interleaved 32kv], 72B rows

    const int jt = blockIdx.x, sp = blockIdx.y, b = blockIdx.z;
    const int nt_all = jt + 1;                  // 64-kv tiles covering the causal range
    const int kt0 = sp * 4;
    if (kt0 >= nt_all) return;
    const int kt_end = min(kt0 + 4, nt_all);

    const int tid = threadIdx.x;
    const int w = tid >> 6, lane = tid & 63, lg = lane >> 4, lr = lane & 15;
    const int qrow_base = jt * 64 + w * 16;

    const u16* kbB = kb + ((size_t)(b << 11)) * H_;
    const u16* vbB = vT + (size_t)b * 128 * 2048;

    // K staging: 4 x 1KB chunks per wave (16KB tile), pre-swizzled source
    unsigned krow[4], kcolb[4];
#pragma unroll
    for (int i = 0; i < 4; ++i) {
        const unsigned o_ = (unsigned)(w * 4 + i) * 1024u + (unsigned)lane * 16u;
        const unsigned o2 = o_ ^ (((o_ >> 8) & 7u) << 4);
        krow[i] = o2 >> 8; kcolb[i] = o2 & 255u;
    }
    // V staging: per half, 2 x u16x8 per thread
    int vd[2], vc[2];
#pragma unroll
    for (int i = 0; i < 2; ++i) {
        const int idx = i * 256 + tid;
        vd[i] = idx >> 2; vc[i] = idx & 3;
    }

    // Q fragments: d-slot map = kc*32 + lg*8 + j  (matches K-frag map)
    const u16* qp = qb + ((size_t)(b << 11) + qrow_base + lr) * H_;
    bf16x8 qf[4];
#pragma unroll
    for (int kc = 0; kc < 4; ++kc)
        qf[kc] = *(const bf16x8*)&qp[kc * 32 + lg * 8];

    u16x8 vr[4];   // [half][i]
    // ---- prologue: stage tile kt0 into buffer 0
    {
        const u16* kbase = kbB + (size_t)kt0 * 64 * H_;
#pragma unroll
        for (int i = 0; i < 4; ++i)
            load_lds16((const char*)kbase + krow[i] * 256 + kcolb[i], &ks[0][(w * 4 + i) * 512]);
        const u16* vbase = vbB + (size_t)kt0 * 64;
#pragma unroll
        for (int h = 0; h < 2; ++h)
#pragma unroll
            for (int i = 0; i < 2; ++i)
                vr[h * 2 + i] = *(const u16x8*)&vbase[(size_t)vd[i] * 2048 + h * 32 + vc[i] * 8];
#pragma unroll
        for (int h = 0; h < 2; ++h)
#pragma unroll
            for (int i = 0; i < 2; ++i) {
                char* rb = (char*)vs[0] + h * 9216 + vd[i] * 72 + (vc[i] & 2) * 4;
                *(u16x4*)(rb + ((2 * vc[i]) & 3) * 16)     = __builtin_shufflevector(vr[h * 2 + i], vr[h * 2 + i], 0, 1, 2, 3);
                *(u16x4*)(rb + ((2 * vc[i] + 1) & 3) * 16) = __builtin_shufflevector(vr[h * 2 + i], vr[h * 2 + i], 4, 5, 6, 7);
            }
    }
    __syncthreads();

    f32x4 o[8] = {};
    float m_run = -1e30f, l_run = 0.f;
    int cur = 0;

    for (int kt = kt0; kt < kt_end; ++kt) {
        const bool pf = (kt + 1 < kt_end);
        // ---- issue prefetch of tile kt+1
        if (pf) {
            const u16* kbase = kbB + (size_t)(kt + 1) * 64 * H_;
#pragma unroll
            for (int i = 0; i < 4; ++i)
                load_lds16((const char*)kbase + krow[i] * 256 + kcolb[i],
                           &ks[cur ^ 1][(w * 4 + i) * 512]);
            const u16* vbase = vbB + (size_t)(kt + 1) * 64;
#pragma unroll
            for (int h = 0; h < 2; ++h)
#pragma unroll
                for (int i = 0; i < 2; ++i)
                    vr[h * 2 + i] = *(const u16x8*)&vbase[(size_t)vd[i] * 2048 + h * 32 + vc[i] * 8];
        }

        // ---- S^T = K @ Q^T : four 16-kv subtiles
        f32x4 sS[4] = {};
        const unsigned swz = ((unsigned)lr & 7u) << 4;
#pragma unroll
        for (int kc = 0; kc < 4; ++kc) {
            const unsigned byte = ((unsigned)(kc * 64 + lg * 16)) ^ swz;
#pragma unroll
            for (int si = 0; si < 4; ++si) {
                const bf16x8 kf = *(const bf16x8*)((const char*)ks[cur] + si * 4096 + lr * 256 + byte);
                sS[si] = __builtin_amdgcn_mfma_f32_16x16x32_bf16(kf, qf[kc], sS[si], 0, 0, 0);
            }
        }

        // causal mask (boundary tiles only), global indices
        if (kt * 64 + 63 > qrow_base) {
            const int qg = qrow_base + lr;
#pragma unroll
            for (int si = 0; si < 4; ++si) {
                const int kvb = kt * 64 + si * 16 + lg * 4;
#pragma unroll
                for (int r = 0; r < 4; ++r)
                    if (kvb + r > qg) sS[si][r] = -INFINITY;
            }
        }

        // online softmax with defer-max (q-row = lr, replicated across 4 lane-groups)
        float mt = fmaxf(fmaxf(fmaxf(sS[0][0], sS[0][1]), fmaxf(sS[0][2], sS[0][3])),
                         fmaxf(fmaxf(sS[1][0], sS[1][1]), fmaxf(sS[1][2], sS[1][3])));
        mt = fmaxf(mt, fmaxf(fmaxf(fmaxf(sS[2][0], sS[2][1]), fmaxf(sS[2][2], sS[2][3])),
                             fmaxf(fmaxf(sS[3][0], sS[3][1]), fmaxf(sS[3][2], sS[3][3]))));
        mt = fmaxf(mt, __shfl_xor(mt, 16));
        mt = fmaxf(mt, __shfl_xor(mt, 32));
        if (__any(mt > m_run + 8.f)) {
            const float mn = fmaxf(m_run, mt);
            const float f = __expf(m_run - mn);
            const float fb0 = __shfl(f, lg * 4 + 0);
            const float fb1 = __shfl(f, lg * 4 + 1);
            const float fb2 = __shfl(f, lg * 4 + 2);
            const float fb3 = __shfl(f, lg * 4 + 3);
#pragma unroll
            for (int ni = 0; ni < 8; ++ni) {
                o[ni][0] *= fb0; o[ni][1] *= fb1; o[ni][2] *= fb2; o[ni][3] *= fb3;
            }
            l_run *= f;
            m_run = mn;
        }
        float p[16];
#pragma unroll
        for (int si = 0; si < 4; ++si)
#pragma unroll
            for (int r = 0; r < 4; ++r)
                p[si * 4 + r] = __expf(sS[si][r] - m_run);
        float sum = ((p[0] + p[1]) + (p[2] + p[3])) + ((p[4] + p[5]) + (p[6] + p[7]))
                  + ((p[8] + p[9]) + (p[10] + p[11])) + ((p[12] + p[13]) + (p[14] + p[15]));
        sum += __shfl_xor(sum, 16);
        sum += __shfl_xor(sum, 32);
        l_run += sum;

        // P -> bf16 A-frags (slot (g,j) -> kv = 4g + (j&3) + 16*(j>>2) within half)
        bf16x8 pa0, pa1;
#pragma unroll
        for (int r = 0; r < 4; ++r) {
            pa0[r] = (__bf16)p[r];      pa0[4 + r] = (__bf16)p[4 + r];
            pa1[r] = (__bf16)p[8 + r];  pa1[4 + r] = (__bf16)p[12 + r];
        }

        // PV: O[16q x 128d] += P @ V, two chained MFMAs per col-tile
#pragma unroll
        for (int ni = 0; ni < 8; ++ni) {
            const bf16x8 vf0 = *(const bf16x8*)((const char*)vs[cur] + (ni * 16 + lr) * 72 + lg * 16);
            const bf16x8 vf1 = *(const bf16x8*)((const char*)vs[cur] + 9216 + (ni * 16 + lr) * 72 + lg * 16);
            o[ni] = __builtin_amdgcn_mfma_f32_16x16x32_bf16(pa0, vf0, o[ni], 0, 0, 0);
            o[ni] = __builtin_amdgcn_mfma_f32_16x16x32_bf16(pa1, vf1, o[ni], 0, 0, 0);
        }

        // ---- land prefetched V, then barrier (drains K gloads too)
        if (pf) {
#pragma unroll
            for (int h = 0; h < 2; ++h)
#pragma unroll
                for (int i = 0; i < 2; ++i) {
                    char* rb = (char*)vs[cur ^ 1] + h * 9216 + vd[i] * 72 + (vc[i] & 2) * 4;
                    *(u16x4*)(rb + ((2 * vc[i]) & 3) * 16)     = __builtin_shufflevector(vr[h * 2 + i], vr[h * 2 + i], 0, 1, 2, 3);
                    *(u16x4*)(rb + ((2 * vc[i] + 1) & 3) * 16) = __builtin_shufflevector(vr[h * 2 + i], vr[h * 2 + i], 4, 5, 6, 7);
                }
        }
        __syncthreads();
        cur ^= 1;
    }

    // write partials (bf16) — slot math identical to r13
    const int a = jt >> 2, b3 = jt & 3;
    const int slot = (a + 1) * (2 * a + b3) + sp;
    u16* pob = po + (size_t)(b * 144 + slot) * 64 * 128;
#pragma unroll
    for (int ni = 0; ni < 8; ++ni) {
        const int col = ni * 16 + lr;
#pragma unroll
        for (int rj = 0; rj < 4; ++rj)
            pob[(w * 16 + lg * 4 + rj) * 128 + col] = f2bf(o[ni][rj]);
    }
    if (lg == 0) {
        float* mlb = ml + (size_t)(b * 144 + slot) * 128;
        mlb[w * 16 + lr] = m_run;
        mlb[64 + w * 16 + lr] = l_run;
    }
}

// ---------------------------------------------------------------------------
// Combine split-K partials (up to 8, bf16 po). grid (256, 4), block 256.
// ---------------------------------------------------------------------------
__global__ __launch_bounds__(256) void attn_combine(
    const u16* __restrict__ po, const float* __restrict__ ml,
    float* __restrict__ out)
{
    const int rid = (blockIdx.x << 3) + (threadIdx.x >> 5);   // row in batch, 0..2047
    const int b = blockIdx.y;
    const int d4 = (threadIdx.x & 31) * 4;
    const int jt = rid >> 6, row = rid & 63;
    const int a = jt >> 2, b3 = jt & 3;
    const int slot0 = (a + 1) * (2 * a + b3);
    const int c = a + 1;                                       // active splits (1..8)

    float M = -INFINITY;
#pragma unroll
    for (int si = 0; si < 8; ++si)
        if (si < c) M = fmaxf(M, ml[(size_t)(b * 144 + slot0 + si) * 128 + row]);

    float L = 0.f;
    float a0 = 0.f, a1 = 0.f, a2 = 0.f, a3 = 0.f;
#pragma unroll
    for (int si = 0; si < 8; ++si) {
        if (si < c) {
            const float* mlb = ml + (size_t)(b * 144 + slot0 + si) * 128;
            const float wgt = __expf(mlb[row] - M);
            L += wgt * mlb[64 + row];
            const u16x4 t = *(const u16x4*)&po[((size_t)(b * 144 + slot0 + si) * 64 + row) * 128 + d4];
            a0 = fmaf(wgt, bf2f(t[0]), a0); a1 = fmaf(wgt, bf2f(t[1]), a1);
            a2 = fmaf(wgt, bf2f(t[2]), a2); a3 = fmaf(wgt, bf2f(t[3]), a3);
        }
    }
    const float inv = 1.f / L;
    *(float4*)&out[((size_t)(b << 11) + rid) * H_ + d4] =
        make_float4(a0 * inv, a1 * inv, a2 * inv, a3 * inv);
}

extern "C" void kernel_launch(void* const* d_in, const int* in_sizes, int n_in,
                              void* d_out, int out_size, void* d_ws, size_t ws_size,
                              hipStream_t stream) {
    const float* x  = (const float*)d_in[0];
    const float* Wk = (const float*)d_in[1];
    const float* Wq = (const float*)d_in[2];
    const float* Wv = (const float*)d_in[3];
    float* out = (float*)d_out;

    u16* po   = (u16*)((char*)d_ws + PO_OFF);
    float* ml = (float*)((char*)d_ws + ML_OFF);
    u16* wbT  = (u16*)((char*)d_ws + WBT_OFF);
    u16* qb   = (u16*)((char*)d_ws + QB_OFF);
    u16* kb   = (u16*)((char*)d_ws + KB_OFF);
    u16* vT   = (u16*)((char*)d_ws + VT_OFF);

    convert_w<<<1536, 256, 0, stream>>>(Wq, Wk, Wv, wbT);
    gemm_qkv<<<dim3(256, 3), 256, 0, stream>>>(x, wbT, qb, kb, vT);
    attn_split<<<dim3(32, 8, 4), 256, 0, stream>>>(qb, kb, vT, po, ml);
    attn_combine<<<dim3(256, 4), 256, 0, stream>>>(po, ml, out);
}

// Round 24
// 58.080 us; speedup vs baseline: 1.3198x; 1.0158x over previous
//
#include <hip/hip_runtime.h>
#include <hip/hip_bf16.h>
#include <math.h>

#define B_ 4
#define T_ 2048
#define C_ 1024
#define H_ 128
#define SCALE 0.088388347648318447f   // 1/sqrt(128)

typedef unsigned short u16;
typedef __bf16 bf16x8 __attribute__((ext_vector_type(8)));
typedef float  f32x4  __attribute__((ext_vector_type(4)));
typedef u16    u16x8  __attribute__((ext_vector_type(8)));
typedef u16    u16x4  __attribute__((ext_vector_type(4)));

// ws byte offsets (ws ~256MB; all regions disjoint)
#define PO_OFF  0u            // bf16 [4][144][64][128] =  9,437,184 B
#define ML_OFF  18874368u     // f32 [4][144][2][64]    =    294,912 B
#define WBT_OFF 19169280u     // bf16 [3][128][1024]    =    786,432 B
#define QB_OFF  19955712u     // bf16 [4][2048][128]    =  2,097,152 B
#define KB_OFF  22052864u     // bf16 [4][2048][128]    =  2,097,152 B
#define VT_OFF  24150016u     // bf16 [4][128][2048]    =  2,097,152 B

__device__ __forceinline__ u16 f2bf(float f) {
    __hip_bfloat16 h = __float2bfloat16(f);
    return __builtin_bit_cast(u16, h);
}
__device__ __forceinline__ float bf2f(u16 u) {
    unsigned v = (unsigned)u << 16;          // bf16 -> f32 is exact
    return __builtin_bit_cast(float, v);
}

// async global->LDS, 16B per lane. lds dst must be wave-uniform base (HW adds lane*16).
__device__ __forceinline__ void load_lds16(const void* g, void* l) {
    __builtin_amdgcn_global_load_lds(
        (const __attribute__((address_space(1))) unsigned int*)g,
        (__attribute__((address_space(3))) unsigned int*)l, 16, 0, 0);
}

// ---------------------------------------------------------------------------
// convert + transpose W: wbT[s][n][k] = W_s[k][n] (bf16), SCALE folded into Wq
// ---------------------------------------------------------------------------
__global__ __launch_bounds__(256) void convert_w(const float* __restrict__ Wq,
                                                 const float* __restrict__ Wk,
                                                 const float* __restrict__ Wv,
                                                 u16* __restrict__ wbT) {
    const int id = blockIdx.x * 256 + threadIdx.x;      // < 3*131072
    const int s = id >> 17;
    const int r = id & 131071;
    const int k = r >> 7, n = r & 127;
    const float* W = (s == 0) ? Wq : (s == 1) ? Wk : Wv;
    float v = W[k * 128 + n];
    if (s == 0) v *= SCALE;
    wbT[(s << 17) + (n << 10) + k] = f2bf(v);
}

// ---------------------------------------------------------------------------
// QKV GEMM (r13 tile, XCD co-location swizzle): bf16 MFMA, fp32 x converted
// in-kernel, 2-deep pipelined staging. grid (768), block 256 (4 waves).
// Tile 32(M)x128(N), BK=64. All 3 W-slices of the same m0 map to the SAME
// XCD (bid&7) so the fp32 x tile is HBM-fetched once and L2-hit twice.
// ---------------------------------------------------------------------------
__global__ __launch_bounds__(256) void gemm_qkv(
    const float* __restrict__ x, const u16* __restrict__ wbT,
    u16* __restrict__ qb, u16* __restrict__ kb, u16* __restrict__ vT)
{
    __shared__ u16 xs[2][2048];   // [32][64] bf16, 128B rows, swizzle ^((row&7)<<4)
    __shared__ u16 ws[2][8192];   // [128 n][64 k] bf16, 128B rows, same swizzle

    const int tid = threadIdx.x;
    const int w = tid >> 6, lane = tid & 63, lg = lane >> 4, lr = lane & 15;
    const int wm = w >> 1, wn = w & 1;

    // XCD co-location: bid&7 = XCD (round-robin dispatch heuristic); the 96
    // work items per XCD enumerate (m0-group, slice) with slice innermost.
    const int bid = blockIdx.x;            // 0..767
    const int xcd = bid & 7;
    const int kk = bid >> 3;               // 0..95
    const int m0 = (xcd * 32 + kk / 3) * 32;
    const int s  = kk % 3;
    const u16* wsrc = wbT + (s << 17);

    // x staging role: 8 threads per row, 8 fp32 (2 float4) per thread
    const int xrow = tid >> 3;       // 0..31
    const int xseg = tid & 7;        // 0..7
    const float* xbase = x + (size_t)(m0 + xrow) * C_ + xseg * 8;
    const unsigned xsw = ((unsigned)xrow & 7u) << 4;

    // W staging addresses (pre-swizzled source), 4 x 1KB chunks per wave
    unsigned wro[4], wco[4];
#pragma unroll
    for (int i = 0; i < 4; ++i) {
        const unsigned o = (unsigned)(w * 4 + i) * 1024u + (unsigned)lane * 16u;
        const unsigned o2 = o ^ (((o >> 7) & 7u) << 4);
        wro[i] = o2 >> 7; wco[i] = (o2 & 127u) >> 1;
    }

    f32x4 acc[4] = {};

    // ---- prologue: stage k0=0 into buf 0
    {
        const float4 f0 = ((const float4*)xbase)[0], f1 = ((const float4*)xbase)[1];
#pragma unroll
        for (int i = 0; i < 4; ++i)
            load_lds16(wsrc + (size_t)wro[i] * C_ + wco[i], &ws[0][(w * 4 + i) * 512]);
        u16x8 pk;
        pk[0] = f2bf(f0.x); pk[1] = f2bf(f0.y); pk[2] = f2bf(f0.z); pk[3] = f2bf(f0.w);
        pk[4] = f2bf(f1.x); pk[5] = f2bf(f1.y); pk[6] = f2bf(f1.z); pk[7] = f2bf(f1.w);
        *(u16x8*)((char*)xs[0] + xrow * 128 + (((unsigned)xseg * 16) ^ xsw)) = pk;
    }
    __syncthreads();

    int buf = 0;
    for (int k0 = 0; k0 < C_; k0 += 64) {
        const bool pf = (k0 + 64 < C_);
        float4 g0, g1;
        if (pf) {
            const float* xn = xbase + k0 + 64;
            g0 = ((const float4*)xn)[0]; g1 = ((const float4*)xn)[1];
#pragma unroll
            for (int i = 0; i < 4; ++i)
                load_lds16(wsrc + (size_t)wro[i] * C_ + (k0 + 64) + wco[i],
                           &ws[buf ^ 1][(w * 4 + i) * 512]);
        }

        // ---- compute from buf
        const int arow = wm * 16 + lr;
        const unsigned asw = ((unsigned)arow & 7u) << 4;
#pragma unroll
        for (int kc = 0; kc < 2; ++kc) {
            const unsigned kb_ = (unsigned)(kc * 64 + lg * 16);
            const bf16x8 af = *(const bf16x8*)((const char*)xs[buf] + arow * 128 + (kb_ ^ asw));
            bf16x8 bfr[4];
#pragma unroll
            for (int ni = 0; ni < 4; ++ni) {
                const int n = wn * 64 + ni * 16 + lr;
                bfr[ni] = *(const bf16x8*)((const char*)ws[buf] + n * 128 + (kb_ ^ (((unsigned)n & 7u) << 4)));
            }
#pragma unroll
            for (int ni = 0; ni < 4; ++ni)
                acc[ni] = __builtin_amdgcn_mfma_f32_16x16x32_bf16(af, bfr[ni], acc[ni], 0, 0, 0);
        }

        // ---- land converted x(k0+64) into buf^1
        if (pf) {
            u16x8 pk;
            pk[0] = f2bf(g0.x); pk[1] = f2bf(g0.y); pk[2] = f2bf(g0.z); pk[3] = f2bf(g0.w);
            pk[4] = f2bf(g1.x); pk[5] = f2bf(g1.y); pk[6] = f2bf(g1.z); pk[7] = f2bf(g1.w);
            *(u16x8*)((char*)xs[buf ^ 1] + xrow * 128 + (((unsigned)xseg * 16) ^ xsw)) = pk;
        }
        __syncthreads();
        buf ^= 1;
    }

    if (s < 2) {
        u16* dst = (s == 0) ? qb : kb;
#pragma unroll
        for (int ni = 0; ni < 4; ++ni) {
            const int trow = m0 + wm * 16 + lg * 4;
            const int col = wn * 64 + ni * 16 + lr;
#pragma unroll
            for (int r = 0; r < 4; ++r)
                dst[(size_t)(trow + r) * H_ + col] = f2bf(acc[ni][r]);
        }
    } else {
        // v stored transposed: vT[b][d][t]
#pragma unroll
        for (int ni = 0; ni < 4; ++ni) {
            const int trow = m0 + wm * 16 + lg * 4;
            const int bb = trow >> 11, t = trow & 2047;
            const int d = wn * 64 + ni * 16 + lr;
            u16x4 pk;
            pk[0] = f2bf(acc[ni][0]); pk[1] = f2bf(acc[ni][1]);
            pk[2] = f2bf(acc[ni][2]); pk[3] = f2bf(acc[ni][3]);
            *(u16x4*)&vT[((size_t)bb * 128 + d) * 2048 + t] = pk;
        }
    }
}

// ---------------------------------------------------------------------------
// Flash attention, KVBLK=64 (r21 version, best measured): split-K chunks of
// 4 big-tiles (256 kv). 64 q-rows/block (4 waves), double-buffered K/V,
// defer-max softmax, bf16 partials. grid (32, 8, 4), block 256.
// ---------------------------------------------------------------------------
__global__ __launch_bounds__(256) void attn_split(
    const u16* __restrict__ qb, const u16* __restrict__ kb,
    const u16* __restrict__ vT, u16* __restrict__ po, float* __restrict__ ml)
{
    __shared__ u16 ks[2][8192];      // [64 kv][128 d] bf16, 256B rows, swizzle ^((row&7)<<4)
    __shared__ u16 vs[2][9216];      // 2 halves x [128 d][seg-interleaved 32kv], 72B rows

    const int jt = blockIdx.x, sp = blockIdx.y, b = blockIdx.z;
    const int nt_all = jt + 1;                  // 64-kv tiles covering the causal range
    const int kt0 = sp * 4;
    if (kt0 >= nt_all) return;
    const int kt_end = min(kt0 + 4, nt_all);

    const int tid = threadIdx.x;
    const int w = tid >> 6, lane = tid & 63, lg = lane >> 4, lr = lane & 15;
    const int qrow_base = jt * 64 + w * 16;

    const u16* kbB = kb + ((size_t)(b << 11)) * H_;
    const u16* vbB = vT + (size_t)b * 128 * 2048;

    // K staging: 4 x 1KB chunks per wave (16KB tile), pre-swizzled source
    unsigned krow[4], kcolb[4];
#pragma unroll
    for (int i = 0; i < 4; ++i) {
        const unsigned o_ = (unsigned)(w * 4 + i) * 1024u + (unsigned)lane * 16u;
        const unsigned o2 = o_ ^ (((o_ >> 8) & 7u) << 4);
        krow[i] = o2 >> 8; kcolb[i] = o2 & 255u;
    }
    // V staging: per half, 2 x u16x8 per thread
    int vd[2], vc[2];
#pragma unroll
    for (int i = 0; i < 2; ++i) {
        const int idx = i * 256 + tid;
        vd[i] = idx >> 2; vc[i] = idx & 3;
    }

    // Q fragments: d-slot map = kc*32 + lg*8 + j  (matches K-frag map)
    const u16* qp = qb + ((size_t)(b << 11) + qrow_base + lr) * H_;
    bf16x8 qf[4];
#pragma unroll
    for (int kc = 0; kc < 4; ++kc)
        qf[kc] = *(const bf16x8*)&qp[kc * 32 + lg * 8];

    u16x8 vr[4];   // [half][i]
    // ---- prologue: stage tile kt0 into buffer 0
    {
        const u16* kbase = kbB + (size_t)kt0 * 64 * H_;
#pragma unroll
        for (int i = 0; i < 4; ++i)
            load_lds16((const char*)kbase + krow[i] * 256 + kcolb[i], &ks[0][(w * 4 + i) * 512]);
        const u16* vbase = vbB + (size_t)kt0 * 64;
#pragma unroll
        for (int h = 0; h < 2; ++h)
#pragma unroll
            for (int i = 0; i < 2; ++i)
                vr[h * 2 + i] = *(const u16x8*)&vbase[(size_t)vd[i] * 2048 + h * 32 + vc[i] * 8];
#pragma unroll
        for (int h = 0; h < 2; ++h)
#pragma unroll
            for (int i = 0; i < 2; ++i) {
                char* rb = (char*)vs[0] + h * 9216 + vd[i] * 72 + (vc[i] & 2) * 4;
                *(u16x4*)(rb + ((2 * vc[i]) & 3) * 16)     = __builtin_shufflevector(vr[h * 2 + i], vr[h * 2 + i], 0, 1, 2, 3);
                *(u16x4*)(rb + ((2 * vc[i] + 1) & 3) * 16) = __builtin_shufflevector(vr[h * 2 + i], vr[h * 2 + i], 4, 5, 6, 7);
            }
    }
    __syncthreads();

    f32x4 o[8] = {};
    float m_run = -1e30f, l_run = 0.f;
    int cur = 0;

    for (int kt = kt0; kt < kt_end; ++kt) {
        const bool pf = (kt + 1 < kt_end);
        // ---- issue prefetch of tile kt+1
        if (pf) {
            const u16* kbase = kbB + (size_t)(kt + 1) * 64 * H_;
#pragma unroll
            for (int i = 0; i < 4; ++i)
                load_lds16((const char*)kbase + krow[i] * 256 + kcolb[i],
                           &ks[cur ^ 1][(w * 4 + i) * 512]);
            const u16* vbase = vbB + (size_t)(kt + 1) * 64;
#pragma unroll
            for (int h = 0; h < 2; ++h)
#pragma unroll
                for (int i = 0; i < 2; ++i)
                    vr[h * 2 + i] = *(const u16x8*)&vbase[(size_t)vd[i] * 2048 + h * 32 + vc[i] * 8];
        }

        // ---- S^T = K @ Q^T : four 16-kv subtiles
        f32x4 sS[4] = {};
        const unsigned swz = ((unsigned)lr & 7u) << 4;
#pragma unroll
        for (int kc = 0; kc < 4; ++kc) {
            const unsigned byte = ((unsigned)(kc * 64 + lg * 16)) ^ swz;
#pragma unroll
            for (int si = 0; si < 4; ++si) {
                const bf16x8 kf = *(const bf16x8*)((const char*)ks[cur] + si * 4096 + lr * 256 + byte);
                sS[si] = __builtin_amdgcn_mfma_f32_16x16x32_bf16(kf, qf[kc], sS[si], 0, 0, 0);
            }
        }

        // causal mask (boundary tiles only), global indices
        if (kt * 64 + 63 > qrow_base) {
            const int qg = qrow_base + lr;
#pragma unroll
            for (int si = 0; si < 4; ++si) {
                const int kvb = kt * 64 + si * 16 + lg * 4;
#pragma unroll
                for (int r = 0; r < 4; ++r)
                    if (kvb + r > qg) sS[si][r] = -INFINITY;
            }
        }

        // online softmax with defer-max (q-row = lr, replicated across 4 lane-groups)
        float mt = fmaxf(fmaxf(fmaxf(sS[0][0], sS[0][1]), fmaxf(sS[0][2], sS[0][3])),
                         fmaxf(fmaxf(sS[1][0], sS[1][1]), fmaxf(sS[1][2], sS[1][3])));
        mt = fmaxf(mt, fmaxf(fmaxf(fmaxf(sS[2][0], sS[2][1]), fmaxf(sS[2][2], sS[2][3])),
                             fmaxf(fmaxf(sS[3][0], sS[3][1]), fmaxf(sS[3][2], sS[3][3]))));
        mt = fmaxf(mt, __shfl_xor(mt, 16));
        mt = fmaxf(mt, __shfl_xor(mt, 32));
        if (__any(mt > m_run + 8.f)) {
            const float mn = fmaxf(m_run, mt);
            const float f = __expf(m_run - mn);
            const float fb0 = __shfl(f, lg * 4 + 0);
            const float fb1 = __shfl(f, lg * 4 + 1);
            const float fb2 = __shfl(f, lg * 4 + 2);
            const float fb3 = __shfl(f, lg * 4 + 3);
#pragma unroll
            for (int ni = 0; ni < 8; ++ni) {
                o[ni][0] *= fb0; o[ni][1] *= fb1; o[ni][2] *= fb2; o[ni][3] *= fb3;
            }
            l_run *= f;
            m_run = mn;
        }
        float p[16];
#pragma unroll
        for (int si = 0; si < 4; ++si)
#pragma unroll
            for (int r = 0; r < 4; ++r)
                p[si * 4 + r] = __expf(sS[si][r] - m_run);
        float sum = ((p[0] + p[1]) + (p[2] + p[3])) + ((p[4] + p[5]) + (p[6] + p[7]))
                  + ((p[8] + p[9]) + (p[10] + p[11])) + ((p[12] + p[13]) + (p[14] + p[15]));
        sum += __shfl_xor(sum, 16);
        sum += __shfl_xor(sum, 32);
        l_run += sum;

        // P -> bf16 A-frags (slot (g,j) -> kv = 4g + (j&3) + 16*(j>>2) within half)
        bf16x8 pa0, pa1;
#pragma unroll
        for (int r = 0; r < 4; ++r) {
            pa0[r] = (__bf16)p[r];      pa0[4 + r] = (__bf16)p[4 + r];
            pa1[r] = (__bf16)p[8 + r];  pa1[4 + r] = (__bf16)p[12 + r];
        }

        // PV: O[16q x 128d] += P @ V, two chained MFMAs per col-tile
#pragma unroll
        for (int ni = 0; ni < 8; ++ni) {
            const bf16x8 vf0 = *(const bf16x8*)((const char*)vs[cur] + (ni * 16 + lr) * 72 + lg * 16);
            const bf16x8 vf1 = *(const bf16x8*)((const char*)vs[cur] + 9216 + (ni * 16 + lr) * 72 + lg * 16);
            o[ni] = __builtin_amdgcn_mfma_f32_16x16x32_bf16(pa0, vf0, o[ni], 0, 0, 0);
            o[ni] = __builtin_amdgcn_mfma_f32_16x16x32_bf16(pa1, vf1, o[ni], 0, 0, 0);
        }

        // ---- land prefetched V, then barrier (drains K gloads too)
        if (pf) {
#pragma unroll
            for (int h = 0; h < 2; ++h)
#pragma unroll
                for (int i = 0; i < 2; ++i) {
                    char* rb = (char*)vs[cur ^ 1] + h * 9216 + vd[i] * 72 + (vc[i] & 2) * 4;
                    *(u16x4*)(rb + ((2 * vc[i]) & 3) * 16)     = __builtin_shufflevector(vr[h * 2 + i], vr[h * 2 + i], 0, 1, 2, 3);
                    *(u16x4*)(rb + ((2 * vc[i] + 1) & 3) * 16) = __builtin_shufflevector(vr[h * 2 + i], vr[h * 2 + i], 4, 5, 6, 7);
                }
        }
        __syncthreads();
        cur ^= 1;
    }

    // write partials (bf16) — slot math identical to r13
    const int a = jt >> 2, b3 = jt & 3;
    const int slot = (a + 1) * (2 * a + b3) + sp;
    u16* pob = po + (size_t)(b * 144 + slot) * 64 * 128;
#pragma unroll
    for (int ni = 0; ni < 8; ++ni) {
        const int col = ni * 16 + lr;
#pragma unroll
        for (int rj = 0; rj < 4; ++rj)
            pob[(w * 16 + lg * 4 + rj) * 128 + col] = f2bf(o[ni][rj]);
    }
    if (lg == 0) {
        float* mlb = ml + (size_t)(b * 144 + slot) * 128;
        mlb[w * 16 + lr] = m_run;
        mlb[64 + w * 16 + lr] = l_run;
    }
}

// ---------------------------------------------------------------------------
// Combine split-K partials (up to 8, bf16 po). grid (256, 4), block 256.
// ---------------------------------------------------------------------------
__global__ __launch_bounds__(256) void attn_combine(
    const u16* __restrict__ po, const float* __restrict__ ml,
    float* __restrict__ out)
{
    const int rid = (blockIdx.x << 3) + (threadIdx.x >> 5);   // row in batch, 0..2047
    const int b = blockIdx.y;
    const int d4 = (threadIdx.x & 31) * 4;
    const int jt = rid >> 6, row = rid & 63;
    const int a = jt >> 2, b3 = jt & 3;
    const int slot0 = (a + 1) * (2 * a + b3);
    const int c = a + 1;                                       // active splits (1..8)

    float M = -INFINITY;
#pragma unroll
    for (int si = 0; si < 8; ++si)
        if (si < c) M = fmaxf(M, ml[(size_t)(b * 144 + slot0 + si) * 128 + row]);

    float L = 0.f;
    float a0 = 0.f, a1 = 0.f, a2 = 0.f, a3 = 0.f;
#pragma unroll
    for (int si = 0; si < 8; ++si) {
        if (si < c) {
            const float* mlb = ml + (size_t)(b * 144 + slot0 + si) * 128;
            const float wgt = __expf(mlb[row] - M);
            L += wgt * mlb[64 + row];
            const u16x4 t = *(const u16x4*)&po[((size_t)(b * 144 + slot0 + si) * 64 + row) * 128 + d4];
            a0 = fmaf(wgt, bf2f(t[0]), a0); a1 = fmaf(wgt, bf2f(t[1]), a1);
            a2 = fmaf(wgt, bf2f(t[2]), a2); a3 = fmaf(wgt, bf2f(t[3]), a3);
        }
    }
    const float inv = 1.f / L;
    *(float4*)&out[((size_t)(b << 11) + rid) * H_ + d4] =
        make_float4(a0 * inv, a1 * inv, a2 * inv, a3 * inv);
}

extern "C" void kernel_launch(void* const* d_in, const int* in_sizes, int n_in,
                              void* d_out, int out_size, void* d_ws, size_t ws_size,
                              hipStream_t stream) {
    const float* x  = (const float*)d_in[0];
    const float* Wk = (const float*)d_in[1];
    const float* Wq = (const float*)d_in[2];
    const float* Wv = (const float*)d_in[3];
    float* out = (float*)d_out;

    u16* po   = (u16*)((char*)d_ws + PO_OFF);
    float* ml = (float*)((char*)d_ws + ML_OFF);
    u16* wbT  = (u16*)((char*)d_ws + WBT_OFF);
    u16* qb   = (u16*)((char*)d_ws + QB_OFF);
    u16* kb   = (u16*)((char*)d_ws + KB_OFF);
    u16* vT   = (u16*)((char*)d_ws + VT_OFF);

    convert_w<<<1536, 256, 0, stream>>>(Wq, Wk, Wv, wbT);
    gemm_qkv<<<768, 256, 0, stream>>>(x, wbT, qb, kb, vT);
    attn_split<<<dim3(32, 8, 4), 256, 0, stream>>>(qb, kb, vT, po, ml);
    attn_combine<<<dim3(256, 4), 256, 0, stream>>>(po, ml, out);
}